// Round 9
// baseline (1829.603 us; speedup 1.0000x reference)
//
#include <hip/hip_runtime.h>

// Problem constants
#define N_NODES 4096
#define E_TOT   12288
#define F_NODE  64
#define F_EDGE  16
#define HDIM    128
#define NLAYER  4
#define NGRAPH  256

typedef _Float16 half8 __attribute__((ext_vector_type(8)));
typedef float    f32x4 __attribute__((ext_vector_type(4)));

// ---------------------------------------------------------------------------
// Repack e2_w (+e2_b as a 129th K-chunk) into f16 "fragment-major" layout:
// W2F[((l*129 + k)*32 + chunk)*512 + lane*8 + j]
//   chunk = hc*8 + ot ;  h = hc*32 + (lane>>4)*8 + j ;  o = ot*16 + (lane&15)
// ---------------------------------------------------------------------------
__global__ __launch_bounds__(256)
void k_prep_w2(const float* __restrict__ e2w, const float* __restrict__ e2b,
               _Float16* __restrict__ W2F)
{
    __shared__ _Float16 pg[16384];
    int b = blockIdx.x;                 // 0 .. 4*129-1
    int l = b / 129, k = b - l * 129;
    const float* src = (k < 128) ? (e2w + ((size_t)(l * 128 + k)) * 16384)
                                 : (e2b + (size_t)l * 16384);
    int t = threadIdx.x;
#pragma unroll
    for (int it = 0; it < 16; ++it) {
        int p = it * 1024 + t * 4;      // linear f32 index (h*128+o)
        float4 v = *(const float4*)(src + p);
#pragma unroll
        for (int j4 = 0; j4 < 4; ++j4) {
            int p_ = p + j4;
            int h  = p_ >> 7, o = p_ & 127;
            int idx = ((h >> 5) * 8 + (o >> 4)) * 512
                    + (((h >> 3) & 3) * 16 + (o & 15)) * 8 + (h & 7);
            float val = (j4 == 0) ? v.x : (j4 == 1) ? v.y : (j4 == 2) ? v.z : v.w;
            pg[idx] = (_Float16)val;
        }
    }
    __syncthreads();
    _Float16* dst = W2F + (size_t)b * 16384;
#pragma unroll
    for (int it = 0; it < 8; ++it) {
        int i = it * 2048 + t * 8;
        *(half8*)(dst + i) = *(const half8*)(pg + i);
    }
}

// h = x @ node_w + node_b  (also f16 copy for the MFMA A-operand path)
__global__ __launch_bounds__(128)
void k_node_enc(const float* __restrict__ x, const float* __restrict__ nw,
                const float* __restrict__ nb, float* __restrict__ h,
                _Float16* __restrict__ hf)
{
    __shared__ float xl[F_NODE];
    int n = blockIdx.x, o = threadIdx.x;
    if (o < F_NODE) xl[o] = x[(size_t)n * F_NODE + o];
    __syncthreads();
    float acc = nb[o];
#pragma unroll 8
    for (int f = 0; f < F_NODE; ++f) acc += xl[f] * nw[f * HDIM + o];
    h [(size_t)n * HDIM + o] = acc;
    hf[(size_t)n * HDIM + o] = (_Float16)acc;
}

// in-degree (for mean agg) + out-degree (for src-sort histogram)
__global__ void k_deg(const int* __restrict__ src, const int* __restrict__ dst,
                      int* __restrict__ deg, int* __restrict__ odeg)
{
    int e = blockIdx.x * 256 + threadIdx.x;
    if (e < E_TOT) {
        atomicAdd(&deg[dst[e]], 1);
        atomicAdd(&odeg[src[e]], 1);
    }
}

__global__ void k_invd(const int* __restrict__ deg, float* __restrict__ invd)
{
    int n = blockIdx.x * 256 + threadIdx.x;
    if (n < N_NODES) invd[n] = deg[n] > 0 ? 1.0f / (float)deg[n] : 0.0f;
}

// exclusive scan of odeg[4096] -> rowptr[4097], ocur copy (1 block)
__global__ __launch_bounds__(256)
void k_scan(const int* __restrict__ odeg, int* __restrict__ rowptr,
            int* __restrict__ ocur)
{
    __shared__ int part[256];
    int t = threadIdx.x, base = t * 16;
    int loc[16], s = 0;
#pragma unroll
    for (int i = 0; i < 16; ++i) { loc[i] = s; s += odeg[base + i]; }
    part[t] = s;
    __syncthreads();
    for (int off = 1; off < 256; off <<= 1) {
        int v = (t >= off) ? part[t - off] : 0;
        __syncthreads();
        part[t] += v;
        __syncthreads();
    }
    int pre = t ? part[t - 1] : 0;
#pragma unroll
    for (int i = 0; i < 16; ++i) {
        rowptr[base + i] = pre + loc[i];
        ocur  [base + i] = pre + loc[i];
    }
    if (t == 255) rowptr[4096] = pre + s;
}

// scatter edges into src-sorted order
__global__ void k_sortscatter(const int* __restrict__ src, const int* __restrict__ dst,
                              int* __restrict__ ocur, int* __restrict__ srcS,
                              int* __restrict__ dstS, int* __restrict__ perm)
{
    int e = blockIdx.x * 256 + threadIdx.x;
    if (e < E_TOT) {
        int s = src[e];
        int pos = atomicAdd(&ocur[s], 1);
        srcS[pos] = s;
        dstS[pos] = dst[e];
        perm[pos] = e;
    }
}

// ef = relu(edge_attr @ e1_w[l] + e1_b[l]) in SORTED edge order,
// stored f16 [E][136]; col128 = 1.0 bias chunk.
#define EF_STRIDE 136
__global__ __launch_bounds__(256)
void k_edge_mlp(const float* __restrict__ ea, const int* __restrict__ perm,
                const float* __restrict__ w1, const float* __restrict__ b1,
                _Float16* __restrict__ efg)
{
    __shared__ float al[16][17];
    __shared__ float wl[16][HDIM];
    __shared__ float bl[HDIM];
    int t = threadIdx.x, e0 = blockIdx.x * 16;
    if (t < HDIM) bl[t] = b1[t];
    for (int i = t; i < F_EDGE * HDIM; i += 256) wl[i >> 7][i & 127] = w1[i];
    { int eL = t >> 4, j = t & 15;
      al[eL][j] = ea[(size_t)perm[e0 + eL] * F_EDGE + j]; }
    __syncthreads();
    int e = t >> 4, og = t & 15;
    float acc[8];
#pragma unroll
    for (int j = 0; j < 8; ++j) acc[j] = bl[og * 8 + j];
#pragma unroll
    for (int f = 0; f < F_EDGE; ++f) {
        float a = al[e][f];
#pragma unroll
        for (int j = 0; j < 8; ++j) acc[j] += a * wl[f][og * 8 + j];
    }
    half8 o;
#pragma unroll
    for (int j = 0; j < 8; ++j) o[j] = (_Float16)fmaxf(acc[j], 0.f);
    *(half8*)&efg[(size_t)(e0 + e) * EF_STRIDE + og * 8] = o;
    if (og == 0) efg[(size_t)(e0 + e) * EF_STRIDE + 128] = (_Float16)1.0f;
}

// ---------------------------------------------------------------------------
// v10 (src-grouped proj): per 64-node src-tile and k-slice:
//   per k: proj_k[64][128] = hf[tile] @ W2[k]   (128 MFMA, A static in regs,
//          B pinned-asm streamed from L2, prefetch distance = 1 k)
//   -> LDS (double-buffered, stride 132 for bank uniformity) -> barrier ->
//   each lane MACs msg for its 2 (edge,32-col-chunk) slots (f32 regs).
// FLOPs: 17.3 GFLOP/layer (was 51.9).  No h gather (rows dense after sort).
// KSPLIT=4 (proven 24.6MB atomic profile), grid 64x4=256 blocks, 512 thr.
// Epilogue: atomic scatter into agg[dstS[e]].
// ---------------------------------------------------------------------------
#define KSPLIT 4
#define PSTR 132   // proj LDS row stride (f32): bank-uniform scatter reads

#define ISSUE4()                                                            \
    asm volatile("global_load_dwordx4 %0, %4, %5\n\t"                       \
                 "v_add_u32 %4, 0x2000, %4\n\t"                             \
                 "global_load_dwordx4 %1, %4, %5\n\t"                       \
                 "v_add_u32 %4, 0x2000, %4\n\t"                             \
                 "global_load_dwordx4 %2, %4, %5\n\t"                       \
                 "v_add_u32 %4, 0x2000, %4\n\t"                             \
                 "global_load_dwordx4 %3, %4, %5\n\t"                       \
                 "v_add_u32 %4, 0x2000, %4"                                 \
                 : "=&v"(b0), "=&v"(b1), "=&v"(b2), "=&v"(b3), "+v"(voff)   \
                 : "s"(Bbase))

#define WAIT4()                                                             \
    asm volatile("s_waitcnt vmcnt(0)"                                       \
                 : "+v"(b0), "+v"(b1), "+v"(b2), "+v"(b3))

__global__ __launch_bounds__(512, 1)
void k_msg(const _Float16* __restrict__ W2L,   // layer base: [129][32][512] f16
           const _Float16* __restrict__ efg,   // [E][136] f16 (sorted order)
           const _Float16* __restrict__ hf,    // [N][128] f16
           const int* __restrict__ rowptr,     // [N+1]
           const int* __restrict__ srcS,       // [E] sorted src
           const int* __restrict__ dstS,       // [E] dst in sorted order
           float* __restrict__ agg,            // [N][128] f32
           float* __restrict__ bns1,
           float* __restrict__ bns2)
{
    __shared__ float    projL[2][64 * PSTR];   // 67.6 KB
    __shared__ _Float16 efL[256][40];          // 20.5 KB
    __shared__ int      srcLs[256];

    const int tid  = threadIdx.x;
    const int lane = tid & 63;
    const int w    = tid >> 6;          // wave 0..7 = output col-frag (w*16..+16)
    const int lhi  = lane >> 4;
    const int llo  = lane & 15;

    // XCD-grouped decode: bx%8 -> XCD; XCD pair {2ks,2ks+1} serves slice ks.
    const int bx    = blockIdx.x;
    const int code  = bx & 7;
    const int ks    = code >> 1;
    const int tile  = (bx >> 3) * 2 + (code & 1);         // 0..63
    const int n0    = tile * 64;
    const int kbase = (129 * ks) >> 2;                    // 0,32,64,96
    const int kcnt  = ((129 * (ks + 1)) >> 2) - kbase;    // 32,32,32,33

    if (bx == 0 && tid < HDIM) { bns1[tid] = 0.f; bns2[tid] = 0.f; }

    const int r0 = rowptr[n0];
    const int ne = rowptr[n0 + 64] - r0;   // ~192 avg; capacity 256

    // stage ef k-slice for this tile's edges (ne rows x 5 half8)
    for (int i = tid; i < ne * 5; i += 512) {
        int e = i / 5, c = i - e * 5;
        *(half8*)&efL[e][c * 8] =
            *(const half8*)(efg + (size_t)(r0 + e) * EF_STRIDE + kbase + c * 8);
    }
    for (int i = tid; i < ne; i += 512) srcLs[i] = srcS[r0 + i] - n0;

    // A-operand: dense hf rows n0..n0+63 (NO gather)
    half8 hs[4][4];
#pragma unroll
    for (int rf = 0; rf < 4; ++rf) {
        const _Float16* hp = hf + (size_t)(n0 + rf * 16 + llo) * HDIM + lhi * 8;
#pragma unroll
        for (int hc = 0; hc < 4; ++hc)
            hs[rf][hc] = *(const half8*)(hp + hc * 32);
    }

    asm volatile("s_waitcnt vmcnt(0) lgkmcnt(0)" ::: "memory");
    __syncthreads();

    // slot params: slot = tid + s*512 -> edge = slot>>2, chunk = slot&3
    int  sE[2], sCh[2], sSrc[2], sDst[2];
    bool sV[2];
#pragma unroll
    for (int s = 0; s < 2; ++s) {
        int slot = tid + s * 512;
        sE[s]  = slot >> 2;
        sCh[s] = slot & 3;
        sV[s]  = sE[s] < ne;
        sSrc[s] = sV[s] ? srcLs[sE[s]] : 0;
        sDst[s] = sV[s] ? dstS[r0 + sE[s]] : 0;
    }

    // B stream: frag (k,hc,w) byte = k*32768 + (hc*8+w)*1024 + lane*16
    uint64_t Bbase = (uint64_t)W2L + (size_t)kbase * 32768;
    unsigned voff  = (unsigned)(w * 1024 + lane * 16);

    half8 b0, b1, b2, b3;
    ISSUE4();   // k = 0

    f32x4 m[2][8];
#pragma unroll
    for (int s = 0; s < 2; ++s)
#pragma unroll
        for (int j = 0; j < 8; ++j)
#pragma unroll
            for (int q = 0; q < 4; ++q) m[s][j][q] = 0.f;

    const f32x4 zc = {0.f, 0.f, 0.f, 0.f};

    for (int kk = 0; kk < kcnt; ++kk) {
        WAIT4();
        f32x4 acc[4];
#pragma unroll
        for (int rf = 0; rf < 4; ++rf)
            acc[rf] = __builtin_amdgcn_mfma_f32_16x16x32_f16(hs[rf][0], b0, zc, 0, 0, 0);
#pragma unroll
        for (int rf = 0; rf < 4; ++rf)
            acc[rf] = __builtin_amdgcn_mfma_f32_16x16x32_f16(hs[rf][1], b1, acc[rf], 0, 0, 0);
#pragma unroll
        for (int rf = 0; rf < 4; ++rf)
            acc[rf] = __builtin_amdgcn_mfma_f32_16x16x32_f16(hs[rf][2], b2, acc[rf], 0, 0, 0);
#pragma unroll
        for (int rf = 0; rf < 4; ++rf)
            acc[rf] = __builtin_amdgcn_mfma_f32_16x16x32_f16(hs[rf][3], b3, acc[rf], 0, 0, 0);
        if (kk + 1 < kcnt) ISSUE4();   // prefetch next k's 4 frags

        // proj_k write: row = rf*16+lhi*4+r (node), col = w*16+llo
        float* pb = &projL[kk & 1][0];
#pragma unroll
        for (int rf = 0; rf < 4; ++rf)
#pragma unroll
            for (int r = 0; r < 4; ++r)
                pb[(rf * 16 + lhi * 4 + r) * PSTR + w * 16 + llo] = acc[rf][r];

        __syncthreads();   // proj[kk&1] complete; prior buf fully consumed

        // msg MAC: m[s] += ef[e,kk] * proj_k[src_e][chunk*32 .. +32]
        const float* pr = &projL[kk & 1][0];
#pragma unroll
        for (int s = 0; s < 2; ++s) {
            if (sV[s]) {
                float f = (float)efL[sE[s]][kk];
                const float* row = pr + sSrc[s] * PSTR + sCh[s] * 32;
#pragma unroll
                for (int j = 0; j < 8; ++j) {
                    f32x4 v = *(const f32x4*)(row + j * 4);
                    m[s][j] += v * f;
                }
            }
        }
    }

    // epilogue: atomic scatter into agg[dst]
#pragma unroll
    for (int s = 0; s < 2; ++s) {
        if (sV[s]) {
            float* ap = &agg[(size_t)sDst[s] * HDIM + sCh[s] * 32];
#pragma unroll
            for (int j = 0; j < 8; ++j)
#pragma unroll
                for (int q = 0; q < 4; ++q)
                    atomicAdd(ap + j * 4 + q, m[s][j][q]);
        }
    }
}

// out = agg*inv_deg + h @ root_w[l] + conv_b[l]   (16 rows per block)
// 4x4 register tiles (128 thr); fused BN sum/sumsq via LDS reduce.
__global__ __launch_bounds__(128)
void k_out(const float* __restrict__ agg, const float* __restrict__ invd,
           const float* __restrict__ h, const float* __restrict__ rw,
           const float* __restrict__ cb, float* __restrict__ outb,
           float* __restrict__ bns1, float* __restrict__ bns2)
{
    __shared__ float hl[16][132];
    __shared__ float rb1[128], rb2[128];
    int t = threadIdx.x, n0 = blockIdx.x * 16;
    int rg = t >> 5, cg = t & 31;
    for (int i = t; i < 16 * HDIM; i += 128)
        hl[i >> 7][i & 127] = h[(size_t)(n0 + (i >> 7)) * HDIM + (i & 127)];
    rb1[t] = 0.f; rb2[t] = 0.f;
    __syncthreads();

    f32x4 cbv = *(const f32x4*)&cb[cg * 4];
    f32x4 acc[4];
#pragma unroll
    for (int i = 0; i < 4; ++i) {
        int r = n0 + rg * 4 + i;
        f32x4 a = *(const f32x4*)&agg[(size_t)r * HDIM + cg * 4];
        acc[i] = a * invd[r] + cbv;
    }
    for (int hh = 0; hh < HDIM; hh += 4) {
        f32x4 wv[4], hv[4];
#pragma unroll
        for (int j = 0; j < 4; ++j) wv[j] = *(const f32x4*)&rw[(hh + j) * HDIM + cg * 4];
#pragma unroll
        for (int i = 0; i < 4; ++i) hv[i] = *(const f32x4*)&hl[rg * 4 + i][hh];
#pragma unroll
        for (int i = 0; i < 4; ++i)
#pragma unroll
            for (int j = 0; j < 4; ++j)
                acc[i] += hv[i][j] * wv[j];
    }
    f32x4 s1v = {0.f,0.f,0.f,0.f}, s2v = {0.f,0.f,0.f,0.f};
#pragma unroll
    for (int i = 0; i < 4; ++i) {
        *(f32x4*)&outb[(size_t)(n0 + rg * 4 + i) * HDIM + cg * 4] = acc[i];
        s1v += acc[i];
        s2v += acc[i] * acc[i];
    }
#pragma unroll
    for (int j = 0; j < 4; ++j) {
        atomicAdd(&rb1[cg * 4 + j], s1v[j]);
        atomicAdd(&rb2[cg * 4 + j], s2v[j]);
    }
    __syncthreads();
    atomicAdd(&bns1[t], rb1[t]);
    atomicAdd(&bns2[t], rb2[t]);
}

// h += relu(bn(out)) with mu/rsig derived inline; refresh hf.
// Non-last layers: zero agg for the next layer's atomics.
// Last layer: fused global-mean-pool scatter.
__global__ void k_bn_apply(const float* __restrict__ outb, const float* __restrict__ bns1,
                           const float* __restrict__ bns2, const float* __restrict__ g,
                           const float* __restrict__ b, float* __restrict__ h,
                           _Float16* __restrict__ hf, float* __restrict__ agg,
                           const int* __restrict__ batch, float* __restrict__ pooled,
                           int* __restrict__ cnt, int last)
{
    int i = blockIdx.x * 256 + threadIdx.x;   // < N*128
    int o = i & (HDIM - 1);
    const float inv_n = 1.0f / (float)N_NODES;
    float m   = bns1[o] * inv_n;
    float var = bns2[o] * inv_n - m * m;
    float rs  = rsqrtf(var + 1e-5f);
    float v  = (outb[i] - m) * rs * g[o] + b[o];
    float hn = h[i] + fmaxf(v, 0.f);
    h[i]  = hn;
    hf[i] = (_Float16)hn;
    if (!last) {
        agg[i] = 0.f;
    } else {
        int n  = i >> 7;
        int gg = batch[n];
        atomicAdd(&pooled[(size_t)gg * HDIM + o], hn);
        if (o == 0) atomicAdd(&cnt[gg], 1);
    }
}

__global__ __launch_bounds__(128)
void k_head(const float* __restrict__ pooled, const int* __restrict__ cnt,
            const float* __restrict__ w1, const float* __restrict__ b1,
            const float* __restrict__ w2, const float* __restrict__ b2,
            float* __restrict__ y)
{
    __shared__ float pl[HDIM];
    __shared__ float red[HDIM];
    int g = blockIdx.x, o = threadIdx.x;
    float ic = 1.0f / (float)max(cnt[g], 1);
    pl[o] = pooled[(size_t)g * HDIM + o] * ic;
    __syncthreads();
    float t = b1[o];
#pragma unroll 8
    for (int hh = 0; hh < HDIM; ++hh) t += pl[hh] * w1[hh * HDIM + o];
    t = fmaxf(t, 0.f);
    red[o] = t * w2[o];
    __syncthreads();
    for (int s = 64; s > 0; s >>= 1) {
        if (o < s) red[o] += red[o + s];
        __syncthreads();
    }
    if (o == 0) y[g] = red[0] + b2[0];
}

// ---------------------------------------------------------------------------
extern "C" void kernel_launch(void* const* d_in, const int* in_sizes, int n_in,
                              void* d_out, int out_size, void* d_ws, size_t ws_size,
                              hipStream_t stream)
{
    const float* x      = (const float*)d_in[0];
    const int*   ei     = (const int*)  d_in[1];
    const float* ea     = (const float*)d_in[2];
    const int*   batch  = (const int*)  d_in[3];
    const float* node_w = (const float*)d_in[4];
    const float* node_b = (const float*)d_in[5];
    const float* e1w    = (const float*)d_in[6];
    const float* e1b    = (const float*)d_in[7];
    const float* e2w    = (const float*)d_in[8];
    const float* e2b    = (const float*)d_in[9];
    const float* rw     = (const float*)d_in[10];
    const float* cb     = (const float*)d_in[11];
    const float* bng    = (const float*)d_in[12];
    const float* bnb    = (const float*)d_in[13];
    const float* hw1    = (const float*)d_in[14];
    const float* hb1    = (const float*)d_in[15];
    const float* hw2    = (const float*)d_in[16];
    const float* hb2    = (const float*)d_in[17];
    float* y = (float*)d_out;

    // workspace carve-up (~28 MB, all 256B-aligned chunks)
    char* ws = (char*)d_ws;
    _Float16* W2F  = (_Float16*)ws; ws += 16908288;  // 4*129*16384 f16
    float*    h    = (float*)ws;    ws += 2097152;
    _Float16* hf   = (_Float16*)ws; ws += 1048576;
    _Float16* efg  = (_Float16*)ws; ws += 3342336;   // E*136 f16
    float*    agg  = (float*)ws;    ws += 2097152;   // [N][128] f32
    float*    bns1 = (float*)ws;    ws += 512;
    float*    bns2 = (float*)ws;    ws += 512;
    float*    outb = (float*)ws;    ws += 2097152;
    int*      deg  = (int*)ws;      ws += 16384;
    int*      odeg = (int*)ws;      ws += 16384;     // adjacent to deg: one memset
    float*    invd = (float*)ws;    ws += 16384;
    int*      rowptr = (int*)ws;    ws += 16640;     // 4097 ints (padded)
    int*      ocur = (int*)ws;      ws += 16384;
    int*      srcS = (int*)ws;      ws += 49152;
    int*      dstS = (int*)ws;      ws += 49152;
    int*      perm = (int*)ws;      ws += 49152;
    float*    pooled = (float*)ws;  ws += 131072;
    int*      cnt  = (int*)ws;      ws += 1024;

    const int* src = ei;
    const int* dst = ei + E_TOT;

    k_prep_w2<<<NLAYER * 129, 256, 0, stream>>>(e2w, e2b, W2F);
    k_node_enc<<<N_NODES, 128, 0, stream>>>(x, node_w, node_b, h, hf);
    hipMemsetAsync(deg, 0, 2 * N_NODES * sizeof(int), stream);   // deg + odeg
    k_deg<<<(E_TOT + 255) / 256, 256, 0, stream>>>(src, dst, deg, odeg);
    k_invd<<<(N_NODES + 255) / 256, 256, 0, stream>>>(deg, invd);
    k_scan<<<1, 256, 0, stream>>>(odeg, rowptr, ocur);
    k_sortscatter<<<(E_TOT + 255) / 256, 256, 0, stream>>>(src, dst, ocur,
                                                           srcS, dstS, perm);
    // agg zero for layer 0; pooled+cnt zero (contiguous => one memset)
    hipMemsetAsync(agg, 0, (size_t)N_NODES * HDIM * sizeof(float), stream);
    hipMemsetAsync(pooled, 0, (size_t)NGRAPH * HDIM * sizeof(float) + NGRAPH * sizeof(int), stream);

    for (int l = 0; l < NLAYER; ++l) {
        k_edge_mlp<<<E_TOT / 16, 256, 0, stream>>>(ea, perm,
                                                   e1w + l * F_EDGE * HDIM,
                                                   e1b + l * HDIM, efg);
        k_msg<<<64 * KSPLIT, 512, 0, stream>>>(W2F + (size_t)l * 129 * 16384,
                                               efg, hf, rowptr, srcS, dstS,
                                               agg, bns1, bns2);
        k_out<<<N_NODES / 16, 128, 0, stream>>>(agg, invd, h,
                                                rw + l * HDIM * HDIM,
                                                cb + l * HDIM, outb, bns1, bns2);
        k_bn_apply<<<(N_NODES * HDIM) / 256, 256, 0, stream>>>(
            outb, bns1, bns2, bng + l * HDIM, bnb + l * HDIM, h, hf,
            agg, batch, pooled, cnt, (l == NLAYER - 1) ? 1 : 0);
    }

    k_head<<<NGRAPH, 128, 0, stream>>>(pooled, cnt, hw1, hb1, hw2, hb2, y);
}

// Round 10
// 431.628 us; speedup vs baseline: 4.2388x; 4.2388x over previous
//
#include <hip/hip_runtime.h>

// Problem constants
#define N_NODES 4096
#define E_TOT   12288
#define F_NODE  64
#define F_EDGE  16
#define HDIM    128
#define NLAYER  4
#define NGRAPH  256

typedef _Float16 half8 __attribute__((ext_vector_type(8)));
typedef float    f32x4 __attribute__((ext_vector_type(4)));

// ---------------------------------------------------------------------------
// Repack e2_w (+e2_b as a 129th K-chunk) into f16 "fragment-major" layout:
// W2F[((l*129 + k)*32 + chunk)*512 + lane*8 + j]
//   chunk = hc*8 + ot ;  h = hc*32 + (lane>>4)*8 + j ;  o = ot*16 + (lane&15)
// One block per (l,k) page: coalesced float4 reads -> LDS transpose ->
// coalesced half8 writes.
// ---------------------------------------------------------------------------
__global__ __launch_bounds__(256)
void k_prep_w2(const float* __restrict__ e2w, const float* __restrict__ e2b,
               _Float16* __restrict__ W2F)
{
    __shared__ _Float16 pg[16384];
    int b = blockIdx.x;                 // 0 .. 4*129-1
    int l = b / 129, k = b - l * 129;
    const float* src = (k < 128) ? (e2w + ((size_t)(l * 128 + k)) * 16384)
                                 : (e2b + (size_t)l * 16384);
    int t = threadIdx.x;
#pragma unroll
    for (int it = 0; it < 16; ++it) {
        int p = it * 1024 + t * 4;      // linear f32 index (h*128+o)
        float4 v = *(const float4*)(src + p);
#pragma unroll
        for (int j4 = 0; j4 < 4; ++j4) {
            int p_ = p + j4;
            int h  = p_ >> 7, o = p_ & 127;
            int idx = ((h >> 5) * 8 + (o >> 4)) * 512
                    + (((h >> 3) & 3) * 16 + (o & 15)) * 8 + (h & 7);
            float val = (j4 == 0) ? v.x : (j4 == 1) ? v.y : (j4 == 2) ? v.z : v.w;
            pg[idx] = (_Float16)val;
        }
    }
    __syncthreads();
    _Float16* dst = W2F + (size_t)b * 16384;
#pragma unroll
    for (int it = 0; it < 8; ++it) {
        int i = it * 2048 + t * 8;
        *(half8*)(dst + i) = *(const half8*)(pg + i);
    }
}

// h = x @ node_w + node_b  (also f16 copy for the gather path)
__global__ __launch_bounds__(128)
void k_node_enc(const float* __restrict__ x, const float* __restrict__ nw,
                const float* __restrict__ nb, float* __restrict__ h,
                _Float16* __restrict__ hf)
{
    __shared__ float xl[F_NODE];
    int n = blockIdx.x, o = threadIdx.x;
    if (o < F_NODE) xl[o] = x[(size_t)n * F_NODE + o];
    __syncthreads();
    float acc = nb[o];
#pragma unroll 8
    for (int f = 0; f < F_NODE; ++f) acc += xl[f] * nw[f * HDIM + o];
    h [(size_t)n * HDIM + o] = acc;
    hf[(size_t)n * HDIM + o] = (_Float16)acc;
}

__global__ void k_deg(const int* __restrict__ dst, int* __restrict__ deg)
{
    int e = blockIdx.x * 256 + threadIdx.x;
    if (e < E_TOT) atomicAdd(&deg[dst[e]], 1);
}

__global__ void k_invd(const int* __restrict__ deg, float* __restrict__ invd)
{
    int n = blockIdx.x * 256 + threadIdx.x;
    if (n < N_NODES) invd[n] = deg[n] > 0 ? 1.0f / (float)deg[n] : 0.0f;
}

// ---------------------------------------------------------------------------
// msg[e,o] = sum_k ef[e,k] * (h[src[e],:] @ W2[k,:,:]) ; atomic scatter-add
// into agg (k-split partials merge via the atomics).
// v11 = round-4 champion structure (barrier-free register streaming,
// BM=64, 4 waves col-split, KSPLIT=4, one ks per XCD pair, quarter-granular
// B refill; proven 65.8us) with two contained changes:
//  (a) edge-MLP FUSED into the prologue: each block computes its own
//      64-edge x <=33-col ef slice directly into efs (w1 reads are
//      wave-broadcast; <=144 fma/thread; kills 4 dispatches + efg traffic).
//  (b) the null-result efn software pipeline removed (-4 VGPR).
// ---------------------------------------------------------------------------
#define BM 64
#define KSPLIT 4
__global__ __launch_bounds__(256, 3)
void k_msg(const _Float16* __restrict__ W2L,   // layer base: [129][32][512] f16
           const float* __restrict__ ea,       // [E][16] f32
           const float* __restrict__ w1,       // layer slice [16][128]
           const float* __restrict__ b1,       // layer slice [128]
           const _Float16* __restrict__ hf,    // [N][128] f16
           const int* __restrict__ srcIdx,
           const int* __restrict__ dstIdx,
           float* __restrict__ agg,            // [N][128] f32
           float* __restrict__ bns1,
           float* __restrict__ bns2)
{
    __shared__ float    al[BM][17];     // edge_attr tile (pad: bank-spread)
    __shared__ _Float16 efs[BM][40];    // ef k-slice (<=33 cols + pad)

    const int tid  = threadIdx.x;
    const int lane = tid & 63;
    const int w    = tid >> 6;          // wave 0..3, owns cols [w*32, w*32+32)
    const int lhi  = lane >> 4;         // 0..3
    const int llo  = lane & 15;

    // XCD-grouped decode: bx%8 -> XCD; XCD pair {2ks,2ks+1} serves slice ks.
    const int bx    = blockIdx.x;
    const int ks    = (bx & 7) >> 1;
    const int tile  = (bx >> 3) * 2 + (bx & 1);           // 0..191
    const int e0    = tile * BM;
    const int kbase = (129 * ks) >> 2;                    // 0,32,64,96
    const int kcnt  = ((129 * (ks + 1)) >> 2) - kbase;    // 32,32,32,33

    // zero BN partial sums for the k_out that follows (stream-ordered)
    if (bx == 0 && tid < HDIM) { bns1[tid] = 0.f; bns2[tid] = 0.f; }

    // stage edge_attr tile (64 x 16 f32; 4 scalars/thread)
    {
        int e = tid >> 2, f0 = (tid & 3) * 4;
        const float* p = ea + (size_t)(e0 + e) * F_EDGE + f0;
        al[e][f0 + 0] = p[0];
        al[e][f0 + 1] = p[1];
        al[e][f0 + 2] = p[2];
        al[e][f0 + 3] = p[3];
    }

    // h_src fragments (all 64 rows; every wave needs all rows) in registers
    half8 hs[4][4];
#pragma unroll
    for (int rf = 0; rf < 4; ++rf) {
        int s = srcIdx[e0 + rf * 16 + llo];
        const _Float16* hp = hf + (size_t)s * HDIM + lhi * 8;
#pragma unroll
        for (int hc = 0; hc < 4; ++hc)
            hs[rf][hc] = *(const half8*)(hp + hc * 32);
    }

    __syncthreads();   // al ready

    // fused edge-MLP: ef[e,c] = relu(al[e,:].w1[:,kbase+c] + b1[kbase+c]);
    // col kg==128 is the bias chunk (ef=1).  Thread t: edge tid>>2,
    // col-quarter tid&3 (<=9 cols).  w1/b1 reads are wave-broadcast (16
    // lanes share each address).
    {
        int e = tid >> 2, q = tid & 3;
        int c0 = q * 9;
        int c1 = c0 + 9 < kcnt ? c0 + 9 : kcnt;
        for (int c = c0; c < c1; ++c) {
            int kg = kbase + c;
            float a;
            if (kg == 128) {
                a = 1.0f;
            } else {
                a = b1[kg];
#pragma unroll
                for (int f = 0; f < F_EDGE; ++f) a += al[e][f] * w1[f * HDIM + kg];
                a = fmaxf(a, 0.f);
            }
            efs[e][c] = (_Float16)a;
        }
    }

    __syncthreads();   // efs ready

    // B fragment (hc, cf) at bp + kk*16384 + hc*4096 + cf*512 (f16 units)
    const _Float16* bp = W2L + (size_t)kbase * 16384 + (w * 2) * 512 + lane * 8;

#define LDQ(d0, d1, kk, hc) do {                                            \
        const _Float16* p_ = bp + (size_t)(kk) * 16384 + (hc) * 4096;       \
        d0 = *(const half8*)(p_); d1 = *(const half8*)(p_ + 512);           \
    } while (0)

    half8 b00, b01, b10, b11, b20, b21, b30, b31;
    LDQ(b00, b01, 0, 0);
    LDQ(b10, b11, 0, 1);
    LDQ(b20, b21, 0, 2);
    LDQ(b30, b31, 0, 3);

    f32x4 acc[4][2];
#pragma unroll
    for (int rf = 0; rf < 4; ++rf)
#pragma unroll
        for (int cf = 0; cf < 2; ++cf)
#pragma unroll
            for (int d = 0; d < 4; ++d) acc[rf][cf][d] = 0.f;

    for (int kk = 0; kk < kcnt; ++kk) {
        const bool nx = (kk + 1 < kcnt);
        _Float16 efv[4];
#pragma unroll
        for (int rf = 0; rf < 4; ++rf) efv[rf] = efs[rf * 16 + llo][kk];

        // quarter hc=0
#pragma unroll
        for (int rf = 0; rf < 4; ++rf) {
            half8 av = hs[rf][0] * efv[rf];
            acc[rf][0] = __builtin_amdgcn_mfma_f32_16x16x32_f16(av, b00, acc[rf][0], 0, 0, 0);
            acc[rf][1] = __builtin_amdgcn_mfma_f32_16x16x32_f16(av, b01, acc[rf][1], 0, 0, 0);
        }
        if (nx) LDQ(b00, b01, kk + 1, 0);

        // quarter hc=1
#pragma unroll
        for (int rf = 0; rf < 4; ++rf) {
            half8 av = hs[rf][1] * efv[rf];
            acc[rf][0] = __builtin_amdgcn_mfma_f32_16x16x32_f16(av, b10, acc[rf][0], 0, 0, 0);
            acc[rf][1] = __builtin_amdgcn_mfma_f32_16x16x32_f16(av, b11, acc[rf][1], 0, 0, 0);
        }
        if (nx) LDQ(b10, b11, kk + 1, 1);

        // quarter hc=2
#pragma unroll
        for (int rf = 0; rf < 4; ++rf) {
            half8 av = hs[rf][2] * efv[rf];
            acc[rf][0] = __builtin_amdgcn_mfma_f32_16x16x32_f16(av, b20, acc[rf][0], 0, 0, 0);
            acc[rf][1] = __builtin_amdgcn_mfma_f32_16x16x32_f16(av, b21, acc[rf][1], 0, 0, 0);
        }
        if (nx) LDQ(b20, b21, kk + 1, 2);

        // quarter hc=3
#pragma unroll
        for (int rf = 0; rf < 4; ++rf) {
            half8 av = hs[rf][3] * efv[rf];
            acc[rf][0] = __builtin_amdgcn_mfma_f32_16x16x32_f16(av, b30, acc[rf][0], 0, 0, 0);
            acc[rf][1] = __builtin_amdgcn_mfma_f32_16x16x32_f16(av, b31, acc[rf][1], 0, 0, 0);
        }
        if (nx) LDQ(b30, b31, kk + 1, 3);
    }
#undef LDQ

    // epilogue: scatter-add partial msg into agg[dst]
    // C/D layout: col=lane&15, row=(lane>>4)*4+reg
#pragma unroll
    for (int rf = 0; rf < 4; ++rf) {
#pragma unroll
        for (int r = 0; r < 4; ++r) {
            int row = rf * 16 + lhi * 4 + r;
            int d   = dstIdx[e0 + row];
#pragma unroll
            for (int cf = 0; cf < 2; ++cf) {
                int o = w * 32 + cf * 16 + llo;
                atomicAdd(&agg[(size_t)d * HDIM + o], acc[rf][cf][r]);
            }
        }
    }
}

// out = agg*inv_deg + h @ root_w[l] + conv_b[l]   (16 rows per block)
// 4x4 register tiles (128 thr); fused BN sum/sumsq via LDS reduce.
// (Verified correct in round 9.)
__global__ __launch_bounds__(128)
void k_out(const float* __restrict__ agg, const float* __restrict__ invd,
           const float* __restrict__ h, const float* __restrict__ rw,
           const float* __restrict__ cb, float* __restrict__ outb,
           float* __restrict__ bns1, float* __restrict__ bns2)
{
    __shared__ float hl[16][132];
    __shared__ float rb1[128], rb2[128];
    int t = threadIdx.x, n0 = blockIdx.x * 16;
    int rg = t >> 5, cg = t & 31;
    for (int i = t; i < 16 * HDIM; i += 128)
        hl[i >> 7][i & 127] = h[(size_t)(n0 + (i >> 7)) * HDIM + (i & 127)];
    rb1[t] = 0.f; rb2[t] = 0.f;
    __syncthreads();

    f32x4 cbv = *(const f32x4*)&cb[cg * 4];
    f32x4 acc[4];
#pragma unroll
    for (int i = 0; i < 4; ++i) {
        int r = n0 + rg * 4 + i;
        f32x4 a = *(const f32x4*)&agg[(size_t)r * HDIM + cg * 4];
        acc[i] = a * invd[r] + cbv;
    }
    for (int hh = 0; hh < HDIM; hh += 4) {
        f32x4 wv[4], hv[4];
#pragma unroll
        for (int j = 0; j < 4; ++j) wv[j] = *(const f32x4*)&rw[(hh + j) * HDIM + cg * 4];
#pragma unroll
        for (int i = 0; i < 4; ++i) hv[i] = *(const f32x4*)&hl[rg * 4 + i][hh];
#pragma unroll
        for (int i = 0; i < 4; ++i)
#pragma unroll
            for (int j = 0; j < 4; ++j)
                acc[i] += hv[i][j] * wv[j];
    }
    f32x4 s1v = {0.f,0.f,0.f,0.f}, s2v = {0.f,0.f,0.f,0.f};
#pragma unroll
    for (int i = 0; i < 4; ++i) {
        *(f32x4*)&outb[(size_t)(n0 + rg * 4 + i) * HDIM + cg * 4] = acc[i];
        s1v += acc[i];
        s2v += acc[i] * acc[i];
    }
#pragma unroll
    for (int j = 0; j < 4; ++j) {
        atomicAdd(&rb1[cg * 4 + j], s1v[j]);
        atomicAdd(&rb2[cg * 4 + j], s2v[j]);
    }
    __syncthreads();
    atomicAdd(&bns1[t], rb1[t]);
    atomicAdd(&bns2[t], rb2[t]);
}

// h += relu(bn(out)) with mu/rsig derived inline; refresh hf.
// Non-last layers: zero agg for the next layer's atomics.
// Last layer: fused global-mean-pool scatter.
__global__ void k_bn_apply(const float* __restrict__ outb, const float* __restrict__ bns1,
                           const float* __restrict__ bns2, const float* __restrict__ g,
                           const float* __restrict__ b, float* __restrict__ h,
                           _Float16* __restrict__ hf, float* __restrict__ agg,
                           const int* __restrict__ batch, float* __restrict__ pooled,
                           int* __restrict__ cnt, int last)
{
    int i = blockIdx.x * 256 + threadIdx.x;   // < N*128
    int o = i & (HDIM - 1);
    const float inv_n = 1.0f / (float)N_NODES;
    float m   = bns1[o] * inv_n;
    float var = bns2[o] * inv_n - m * m;
    float rs  = rsqrtf(var + 1e-5f);
    float v  = (outb[i] - m) * rs * g[o] + b[o];
    float hn = h[i] + fmaxf(v, 0.f);
    h[i]  = hn;
    hf[i] = (_Float16)hn;
    if (!last) {
        agg[i] = 0.f;
    } else {
        int n  = i >> 7;
        int gg = batch[n];
        atomicAdd(&pooled[(size_t)gg * HDIM + o], hn);
        if (o == 0) atomicAdd(&cnt[gg], 1);
    }
}

__global__ __launch_bounds__(128)
void k_head(const float* __restrict__ pooled, const int* __restrict__ cnt,
            const float* __restrict__ w1, const float* __restrict__ b1,
            const float* __restrict__ w2, const float* __restrict__ b2,
            float* __restrict__ y)
{
    __shared__ float pl[HDIM];
    __shared__ float red[HDIM];
    int g = blockIdx.x, o = threadIdx.x;
    float ic = 1.0f / (float)max(cnt[g], 1);
    pl[o] = pooled[(size_t)g * HDIM + o] * ic;
    __syncthreads();
    float t = b1[o];
#pragma unroll 8
    for (int hh = 0; hh < HDIM; ++hh) t += pl[hh] * w1[hh * HDIM + o];
    t = fmaxf(t, 0.f);
    red[o] = t * w2[o];
    __syncthreads();
    for (int s = 64; s > 0; s >>= 1) {
        if (o < s) red[o] += red[o + s];
        __syncthreads();
    }
    if (o == 0) y[g] = red[0] + b2[0];
}

// ---------------------------------------------------------------------------
extern "C" void kernel_launch(void* const* d_in, const int* in_sizes, int n_in,
                              void* d_out, int out_size, void* d_ws, size_t ws_size,
                              hipStream_t stream)
{
    const float* x      = (const float*)d_in[0];
    const int*   ei     = (const int*)  d_in[1];
    const float* ea     = (const float*)d_in[2];
    const int*   batch  = (const int*)  d_in[3];
    const float* node_w = (const float*)d_in[4];
    const float* node_b = (const float*)d_in[5];
    const float* e1w    = (const float*)d_in[6];
    const float* e1b    = (const float*)d_in[7];
    const float* e2w    = (const float*)d_in[8];
    const float* e2b    = (const float*)d_in[9];
    const float* rw     = (const float*)d_in[10];
    const float* cb     = (const float*)d_in[11];
    const float* bng    = (const float*)d_in[12];
    const float* bnb    = (const float*)d_in[13];
    const float* hw1    = (const float*)d_in[14];
    const float* hb1    = (const float*)d_in[15];
    const float* hw2    = (const float*)d_in[16];
    const float* hb2    = (const float*)d_in[17];
    float* y = (float*)d_out;

    // workspace carve-up (~24.5 MB, all 256B-aligned chunks)
    char* ws = (char*)d_ws;
    _Float16* W2F  = (_Float16*)ws; ws += 16908288;  // 4*129*16384 f16
    float*    h    = (float*)ws;    ws += 2097152;
    _Float16* hf   = (_Float16*)ws; ws += 1048576;
    float*    agg  = (float*)ws;    ws += 2097152;   // [N][128] f32
    float*    bns1 = (float*)ws;    ws += 512;       // BN sum
    float*    bns2 = (float*)ws;    ws += 512;       // BN sumsq
    float*    outb = (float*)ws;    ws += 2097152;
    int*      deg  = (int*)ws;      ws += 16384;
    float*    invd = (float*)ws;    ws += 16384;
    float*    pooled = (float*)ws;  ws += 131072;
    int*      cnt  = (int*)ws;      ws += 1024;

    const int* src = ei;
    const int* dst = ei + E_TOT;

    k_prep_w2<<<NLAYER * 129, 256, 0, stream>>>(e2w, e2b, W2F);
    k_node_enc<<<N_NODES, 128, 0, stream>>>(x, node_w, node_b, h, hf);
    hipMemsetAsync(deg, 0, N_NODES * sizeof(int), stream);
    k_deg<<<(E_TOT + 255) / 256, 256, 0, stream>>>(dst, deg);
    k_invd<<<(N_NODES + 255) / 256, 256, 0, stream>>>(deg, invd);
    // agg zero for layer 0; pooled+cnt zero (contiguous => one memset)
    hipMemsetAsync(agg, 0, (size_t)N_NODES * HDIM * sizeof(float), stream);
    hipMemsetAsync(pooled, 0, (size_t)NGRAPH * HDIM * sizeof(float) + NGRAPH * sizeof(int), stream);

    for (int l = 0; l < NLAYER; ++l) {
        k_msg<<<(E_TOT / BM) * KSPLIT, 256, 0, stream>>>(
            W2F + (size_t)l * 129 * 16384, ea,
            e1w + l * F_EDGE * HDIM, e1b + l * HDIM,
            hf, src, dst, agg, bns1, bns2);
        k_out<<<N_NODES / 16, 128, 0, stream>>>(agg, invd, h,
                                                rw + l * HDIM * HDIM,
                                                cb + l * HDIM, outb, bns1, bns2);
        k_bn_apply<<<(N_NODES * HDIM) / 256, 256, 0, stream>>>(
            outb, bns1, bns2, bng + l * HDIM, bnb + l * HDIM, h, hf,
            agg, batch, pooled, cnt, (l == NLAYER - 1) ? 1 : 0);
    }

    k_head<<<NGRAPH, 128, 0, stream>>>(pooled, cnt, hw1, hb1, hw2, hb2, y);
}

// Round 11
// 414.867 us; speedup vs baseline: 4.4101x; 1.0404x over previous
//
#include <hip/hip_runtime.h>

// Problem constants
#define N_NODES 4096
#define E_TOT   12288
#define F_NODE  64
#define F_EDGE  16
#define HDIM    128
#define NLAYER  4
#define NGRAPH  256

typedef _Float16 half8 __attribute__((ext_vector_type(8)));
typedef float    f32x4 __attribute__((ext_vector_type(4)));

// ---------------------------------------------------------------------------
// Repack e2_w (+e2_b as a 129th K-chunk) into f16 "fragment-major" layout:
// W2F[((l*129 + k)*32 + chunk)*512 + lane*8 + j]
//   chunk = hc*8 + ot ;  h = hc*32 + (lane>>4)*8 + j ;  o = ot*16 + (lane&15)
// One block per (l,k) page: coalesced float4 reads -> LDS transpose ->
// coalesced half8 writes.
// ---------------------------------------------------------------------------
__global__ __launch_bounds__(256)
void k_prep_w2(const float* __restrict__ e2w, const float* __restrict__ e2b,
               _Float16* __restrict__ W2F)
{
    __shared__ _Float16 pg[16384];
    int b = blockIdx.x;                 // 0 .. 4*129-1
    int l = b / 129, k = b - l * 129;
    const float* src = (k < 128) ? (e2w + ((size_t)(l * 128 + k)) * 16384)
                                 : (e2b + (size_t)l * 16384);
    int t = threadIdx.x;
#pragma unroll
    for (int it = 0; it < 16; ++it) {
        int p = it * 1024 + t * 4;      // linear f32 index (h*128+o)
        float4 v = *(const float4*)(src + p);
#pragma unroll
        for (int j4 = 0; j4 < 4; ++j4) {
            int p_ = p + j4;
            int h  = p_ >> 7, o = p_ & 127;
            int idx = ((h >> 5) * 8 + (o >> 4)) * 512
                    + (((h >> 3) & 3) * 16 + (o & 15)) * 8 + (h & 7);
            float val = (j4 == 0) ? v.x : (j4 == 1) ? v.y : (j4 == 2) ? v.z : v.w;
            pg[idx] = (_Float16)val;
        }
    }
    __syncthreads();
    _Float16* dst = W2F + (size_t)b * 16384;
#pragma unroll
    for (int it = 0; it < 8; ++it) {
        int i = it * 2048 + t * 8;
        *(half8*)(dst + i) = *(const half8*)(pg + i);
    }
}

// h = x @ node_w + node_b  (also f16 copy for the gather path)
__global__ __launch_bounds__(128)
void k_node_enc(const float* __restrict__ x, const float* __restrict__ nw,
                const float* __restrict__ nb, float* __restrict__ h,
                _Float16* __restrict__ hf)
{
    __shared__ float xl[F_NODE];
    int n = blockIdx.x, o = threadIdx.x;
    if (o < F_NODE) xl[o] = x[(size_t)n * F_NODE + o];
    __syncthreads();
    float acc = nb[o];
#pragma unroll 8
    for (int f = 0; f < F_NODE; ++f) acc += xl[f] * nw[f * HDIM + o];
    h [(size_t)n * HDIM + o] = acc;
    hf[(size_t)n * HDIM + o] = (_Float16)acc;
}

__global__ void k_deg(const int* __restrict__ dst, int* __restrict__ deg)
{
    int e = blockIdx.x * 256 + threadIdx.x;
    if (e < E_TOT) atomicAdd(&deg[dst[e]], 1);
}

__global__ void k_invd(const int* __restrict__ deg, float* __restrict__ invd)
{
    int n = blockIdx.x * 256 + threadIdx.x;
    if (n < N_NODES) invd[n] = deg[n] > 0 ? 1.0f / (float)deg[n] : 0.0f;
}

// ef = relu(edge_attr @ e1_w[l] + e1_b[l]) stored f16 [E][136] (16B rows;
// col128 = 1.0 bias chunk, cols 129..135 unused).
// 16 edges per block, 256 thr; w1 (8KB) staged in LDS once per block.
// (Standalone version: measured ~3us/layer; fusing it into k_msg cost +11us
//  per k_msg dispatch in round 10 -- keep separate.)
#define EF_STRIDE 136
__global__ __launch_bounds__(256)
void k_edge_mlp(const float* __restrict__ ea, const float* __restrict__ w1,
                const float* __restrict__ b1, _Float16* __restrict__ efg)
{
    __shared__ float al[16][17];
    __shared__ float wl[16][HDIM];
    __shared__ float bl[HDIM];
    int t = threadIdx.x, e0 = blockIdx.x * 16;
    if (t < HDIM) bl[t] = b1[t];
    for (int i = t; i < F_EDGE * HDIM; i += 256) wl[i >> 7][i & 127] = w1[i];
    { int i = t; al[i >> 4][i & 15] = ea[(size_t)e0 * F_EDGE + i]; }
    __syncthreads();
    int e = t >> 4, og = t & 15;
    float acc[8];
#pragma unroll
    for (int j = 0; j < 8; ++j) acc[j] = bl[og * 8 + j];
#pragma unroll
    for (int f = 0; f < F_EDGE; ++f) {
        float a = al[e][f];
#pragma unroll
        for (int j = 0; j < 8; ++j) acc[j] += a * wl[f][og * 8 + j];
    }
    half8 o;
#pragma unroll
    for (int j = 0; j < 8; ++j) o[j] = (_Float16)fmaxf(acc[j], 0.f);
    *(half8*)&efg[(size_t)(e0 + e) * EF_STRIDE + og * 8] = o;
    if (og == 0) efg[(size_t)(e0 + e) * EF_STRIDE + 128] = (_Float16)1.0f;
}

// ---------------------------------------------------------------------------
// msg[e,o] = sum_k ef[e,k] * (h[src[e],:] @ W2[k,:,:]) ; atomic scatter-add
// into agg (k-split partials merge via the atomics).
// v12 = the measured-best k_msg (round 3: 64.1us, VGPR 76): barrier-free
// register streaming, BM=64, 4 waves col-split, KSPLIT=4 (one ks per XCD
// pair), HALF-granular B double-buffer (B0/B1) refilled right after last
// use.  No efn pipeline, no setprio, no fused MLP (all measured neutral or
// negative).  Block 0 zeroes bns1/bns2 for the following k_out.
// ---------------------------------------------------------------------------
#define BM 64
#define KSPLIT 4
__global__ __launch_bounds__(256, 3)
void k_msg(const _Float16* __restrict__ W2L,   // layer base: [129][32][512] f16
           const _Float16* __restrict__ efg,   // [E][136] f16
           const _Float16* __restrict__ hf,    // [N][128] f16
           const int* __restrict__ srcIdx,
           const int* __restrict__ dstIdx,
           float* __restrict__ agg,            // [N][128] f32
           float* __restrict__ bns1,
           float* __restrict__ bns2)
{
    __shared__ _Float16 efs[BM][40];    // local k-slice of ef (<=33 cols + pad)

    const int tid  = threadIdx.x;
    const int lane = tid & 63;
    const int w    = tid >> 6;          // wave 0..3, owns cols [w*32, w*32+32)
    const int lhi  = lane >> 4;         // 0..3
    const int llo  = lane & 15;

    // XCD-grouped decode: bx%8 -> XCD; XCD pair {2ks,2ks+1} serves slice ks.
    const int bx    = blockIdx.x;
    const int ks    = (bx & 7) >> 1;
    const int tile  = (bx >> 3) * 2 + (bx & 1);           // 0..191
    const int e0    = tile * BM;
    const int kbase = (129 * ks) >> 2;                    // 0,32,64,96
    const int kcnt  = ((129 * (ks + 1)) >> 2) - kbase;    // 32,32,32,33

    // zero BN partial sums for the k_out that follows (stream-ordered)
    if (bx == 0 && tid < HDIM) { bns1[tid] = 0.f; bns2[tid] = 0.f; }

    // stage ef k-slice (64 rows x 5 half8)
    for (int i = tid; i < BM * 5; i += 256) {
        int r = i / 5, c = i - r * 5;
        *(half8*)&efs[r][c * 8] =
            *(const half8*)(efg + (size_t)(e0 + r) * EF_STRIDE + kbase + c * 8);
    }

    // h_src fragments (all 64 rows; every wave needs all rows) in registers
    half8 hs[4][4];
#pragma unroll
    for (int rf = 0; rf < 4; ++rf) {
        int s = srcIdx[e0 + rf * 16 + llo];
        const _Float16* hp = hf + (size_t)s * HDIM + lhi * 8;
#pragma unroll
        for (int hc = 0; hc < 4; ++hc)
            hs[rf][hc] = *(const half8*)(hp + hc * 32);
    }

    __syncthreads();   // efs ready (only barrier in the kernel)

    // B fragment base: chunk = hc*8 + w*2 + cf ; offsets in f16 units:
    //   (kk)*16384 + hc*4096 + cf*512, lane offset lane*8 (16B/lane)
    const _Float16* bp = W2L + (size_t)kbase * 16384 + (w * 2) * 512 + lane * 8;

#define LDH(dst, kk, h2) do {                                          \
        const _Float16* p_ = bp + (size_t)(kk) * 16384 + (h2) * 8192;  \
        dst[0] = *(const half8*)(p_);                                  \
        dst[1] = *(const half8*)(p_ + 512);                            \
        dst[2] = *(const half8*)(p_ + 4096);                           \
        dst[3] = *(const half8*)(p_ + 4608);                           \
    } while (0)

    half8 B0[4], B1[4];
    LDH(B0, 0, 0);      // (k=0, hc 0-1) fragments
    LDH(B1, 0, 1);      // (k=0, hc 2-3) fragments

    f32x4 acc[4][2];
#pragma unroll
    for (int rf = 0; rf < 4; ++rf)
#pragma unroll
        for (int cf = 0; cf < 2; ++cf)
#pragma unroll
            for (int d = 0; d < 4; ++d) acc[rf][cf][d] = 0.f;

    for (int kk = 0; kk < kcnt; ++kk) {
        _Float16 efv[4];
#pragma unroll
        for (int rf = 0; rf < 4; ++rf) efv[rf] = efs[rf * 16 + llo][kk];

        // half 0: hc 0-1 from B0 (compiler inserts counted vmcnt before use)
#pragma unroll
        for (int rf = 0; rf < 4; ++rf) {
            half8 av0 = hs[rf][0] * efv[rf];
            half8 av1 = hs[rf][1] * efv[rf];
            acc[rf][0] = __builtin_amdgcn_mfma_f32_16x16x32_f16(av0, B0[0], acc[rf][0], 0, 0, 0);
            acc[rf][1] = __builtin_amdgcn_mfma_f32_16x16x32_f16(av0, B0[1], acc[rf][1], 0, 0, 0);
            acc[rf][0] = __builtin_amdgcn_mfma_f32_16x16x32_f16(av1, B0[2], acc[rf][0], 0, 0, 0);
            acc[rf][1] = __builtin_amdgcn_mfma_f32_16x16x32_f16(av1, B0[3], acc[rf][1], 0, 0, 0);
        }
        if (kk + 1 < kcnt) LDH(B0, kk + 1, 0);   // refill right after last use

        // half 1: hc 2-3 from B1
#pragma unroll
        for (int rf = 0; rf < 4; ++rf) {
            half8 av2 = hs[rf][2] * efv[rf];
            half8 av3 = hs[rf][3] * efv[rf];
            acc[rf][0] = __builtin_amdgcn_mfma_f32_16x16x32_f16(av2, B1[0], acc[rf][0], 0, 0, 0);
            acc[rf][1] = __builtin_amdgcn_mfma_f32_16x16x32_f16(av2, B1[1], acc[rf][1], 0, 0, 0);
            acc[rf][0] = __builtin_amdgcn_mfma_f32_16x16x32_f16(av3, B1[2], acc[rf][0], 0, 0, 0);
            acc[rf][1] = __builtin_amdgcn_mfma_f32_16x16x32_f16(av3, B1[3], acc[rf][1], 0, 0, 0);
        }
        if (kk + 1 < kcnt) LDH(B1, kk + 1, 1);
    }
#undef LDH

    // epilogue: scatter-add partial msg into agg[dst]
    // C/D layout: col=lane&15, row=(lane>>4)*4+reg
#pragma unroll
    for (int rf = 0; rf < 4; ++rf) {
#pragma unroll
        for (int r = 0; r < 4; ++r) {
            int row = rf * 16 + lhi * 4 + r;
            int d   = dstIdx[e0 + row];
#pragma unroll
            for (int cf = 0; cf < 2; ++cf) {
                int o = w * 32 + cf * 16 + llo;
                atomicAdd(&agg[(size_t)d * HDIM + o], acc[rf][cf][r]);
            }
        }
    }
}

// out = agg*inv_deg + h @ root_w[l] + conv_b[l]   (16 rows per block)
// 4x4 register tiles (128 thr); fused BN sum/sumsq via LDS reduce.
// (Functionally verified rounds 9-10.)
__global__ __launch_bounds__(128)
void k_out(const float* __restrict__ agg, const float* __restrict__ invd,
           const float* __restrict__ h, const float* __restrict__ rw,
           const float* __restrict__ cb, float* __restrict__ outb,
           float* __restrict__ bns1, float* __restrict__ bns2)
{
    __shared__ float hl[16][132];
    __shared__ float rb1[128], rb2[128];
    int t = threadIdx.x, n0 = blockIdx.x * 16;
    int rg = t >> 5, cg = t & 31;
    for (int i = t; i < 16 * HDIM; i += 128)
        hl[i >> 7][i & 127] = h[(size_t)(n0 + (i >> 7)) * HDIM + (i & 127)];
    rb1[t] = 0.f; rb2[t] = 0.f;
    __syncthreads();

    f32x4 cbv = *(const f32x4*)&cb[cg * 4];
    f32x4 acc[4];
#pragma unroll
    for (int i = 0; i < 4; ++i) {
        int r = n0 + rg * 4 + i;
        f32x4 a = *(const f32x4*)&agg[(size_t)r * HDIM + cg * 4];
        acc[i] = a * invd[r] + cbv;
    }
    for (int hh = 0; hh < HDIM; hh += 4) {
        f32x4 wv[4], hv[4];
#pragma unroll
        for (int j = 0; j < 4; ++j) wv[j] = *(const f32x4*)&rw[(hh + j) * HDIM + cg * 4];
#pragma unroll
        for (int i = 0; i < 4; ++i) hv[i] = *(const f32x4*)&hl[rg * 4 + i][hh];
#pragma unroll
        for (int i = 0; i < 4; ++i)
#pragma unroll
            for (int j = 0; j < 4; ++j)
                acc[i] += hv[i][j] * wv[j];
    }
    f32x4 s1v = {0.f,0.f,0.f,0.f}, s2v = {0.f,0.f,0.f,0.f};
#pragma unroll
    for (int i = 0; i < 4; ++i) {
        *(f32x4*)&outb[(size_t)(n0 + rg * 4 + i) * HDIM + cg * 4] = acc[i];
        s1v += acc[i];
        s2v += acc[i] * acc[i];
    }
#pragma unroll
    for (int j = 0; j < 4; ++j) {
        atomicAdd(&rb1[cg * 4 + j], s1v[j]);
        atomicAdd(&rb2[cg * 4 + j], s2v[j]);
    }
    __syncthreads();
    atomicAdd(&bns1[t], rb1[t]);
    atomicAdd(&bns2[t], rb2[t]);
}

// h += relu(bn(out)) with mu/rsig derived inline; refresh hf.
// Non-last layers: zero agg for the next layer's atomics.
// Last layer: fused global-mean-pool scatter.
__global__ void k_bn_apply(const float* __restrict__ outb, const float* __restrict__ bns1,
                           const float* __restrict__ bns2, const float* __restrict__ g,
                           const float* __restrict__ b, float* __restrict__ h,
                           _Float16* __restrict__ hf, float* __restrict__ agg,
                           const int* __restrict__ batch, float* __restrict__ pooled,
                           int* __restrict__ cnt, int last)
{
    int i = blockIdx.x * 256 + threadIdx.x;   // < N*128
    int o = i & (HDIM - 1);
    const float inv_n = 1.0f / (float)N_NODES;
    float m   = bns1[o] * inv_n;
    float var = bns2[o] * inv_n - m * m;
    float rs  = rsqrtf(var + 1e-5f);
    float v  = (outb[i] - m) * rs * g[o] + b[o];
    float hn = h[i] + fmaxf(v, 0.f);
    h[i]  = hn;
    hf[i] = (_Float16)hn;
    if (!last) {
        agg[i] = 0.f;
    } else {
        int n  = i >> 7;
        int gg = batch[n];
        atomicAdd(&pooled[(size_t)gg * HDIM + o], hn);
        if (o == 0) atomicAdd(&cnt[gg], 1);
    }
}

__global__ __launch_bounds__(128)
void k_head(const float* __restrict__ pooled, const int* __restrict__ cnt,
            const float* __restrict__ w1, const float* __restrict__ b1,
            const float* __restrict__ w2, const float* __restrict__ b2,
            float* __restrict__ y)
{
    __shared__ float pl[HDIM];
    __shared__ float red[HDIM];
    int g = blockIdx.x, o = threadIdx.x;
    float ic = 1.0f / (float)max(cnt[g], 1);
    pl[o] = pooled[(size_t)g * HDIM + o] * ic;
    __syncthreads();
    float t = b1[o];
#pragma unroll 8
    for (int hh = 0; hh < HDIM; ++hh) t += pl[hh] * w1[hh * HDIM + o];
    t = fmaxf(t, 0.f);
    red[o] = t * w2[o];
    __syncthreads();
    for (int s = 64; s > 0; s >>= 1) {
        if (o < s) red[o] += red[o + s];
        __syncthreads();
    }
    if (o == 0) y[g] = red[0] + b2[0];
}

// ---------------------------------------------------------------------------
extern "C" void kernel_launch(void* const* d_in, const int* in_sizes, int n_in,
                              void* d_out, int out_size, void* d_ws, size_t ws_size,
                              hipStream_t stream)
{
    const float* x      = (const float*)d_in[0];
    const int*   ei     = (const int*)  d_in[1];
    const float* ea     = (const float*)d_in[2];
    const int*   batch  = (const int*)  d_in[3];
    const float* node_w = (const float*)d_in[4];
    const float* node_b = (const float*)d_in[5];
    const float* e1w    = (const float*)d_in[6];
    const float* e1b    = (const float*)d_in[7];
    const float* e2w    = (const float*)d_in[8];
    const float* e2b    = (const float*)d_in[9];
    const float* rw     = (const float*)d_in[10];
    const float* cb     = (const float*)d_in[11];
    const float* bng    = (const float*)d_in[12];
    const float* bnb    = (const float*)d_in[13];
    const float* hw1    = (const float*)d_in[14];
    const float* hb1    = (const float*)d_in[15];
    const float* hw2    = (const float*)d_in[16];
    const float* hb2    = (const float*)d_in[17];
    float* y = (float*)d_out;

    // workspace carve-up (~27.8 MB, all 256B-aligned chunks)
    char* ws = (char*)d_ws;
    _Float16* W2F  = (_Float16*)ws; ws += 16908288;  // 4*129*16384 f16
    float*    h    = (float*)ws;    ws += 2097152;
    _Float16* hf   = (_Float16*)ws; ws += 1048576;
    _Float16* efg  = (_Float16*)ws; ws += 3342336;   // E*136 f16
    float*    agg  = (float*)ws;    ws += 2097152;   // [N][128] f32
    float*    bns1 = (float*)ws;    ws += 512;       // BN sum
    float*    bns2 = (float*)ws;    ws += 512;       // BN sumsq
    float*    outb = (float*)ws;    ws += 2097152;
    int*      deg  = (int*)ws;      ws += 16384;
    float*    invd = (float*)ws;    ws += 16384;
    float*    pooled = (float*)ws;  ws += 131072;
    int*      cnt  = (int*)ws;      ws += 1024;

    const int* src = ei;
    const int* dst = ei + E_TOT;

    k_prep_w2<<<NLAYER * 129, 256, 0, stream>>>(e2w, e2b, W2F);
    k_node_enc<<<N_NODES, 128, 0, stream>>>(x, node_w, node_b, h, hf);
    hipMemsetAsync(deg, 0, N_NODES * sizeof(int), stream);
    k_deg<<<(E_TOT + 255) / 256, 256, 0, stream>>>(dst, deg);
    k_invd<<<(N_NODES + 255) / 256, 256, 0, stream>>>(deg, invd);
    // agg zero for layer 0; pooled+cnt zero (contiguous => one memset)
    hipMemsetAsync(agg, 0, (size_t)N_NODES * HDIM * sizeof(float), stream);
    hipMemsetAsync(pooled, 0, (size_t)NGRAPH * HDIM * sizeof(float) + NGRAPH * sizeof(int), stream);

    for (int l = 0; l < NLAYER; ++l) {
        k_edge_mlp<<<E_TOT / 16, 256, 0, stream>>>(ea, e1w + l * F_EDGE * HDIM,
                                                   e1b + l * HDIM, efg);
        k_msg<<<(E_TOT / BM) * KSPLIT, 256, 0, stream>>>(
            W2F + (size_t)l * 129 * 16384, efg, hf, src, dst, agg, bns1, bns2);
        k_out<<<N_NODES / 16, 128, 0, stream>>>(agg, invd, h,
                                                rw + l * HDIM * HDIM,
                                                cb + l * HDIM, outb, bns1, bns2);
        k_bn_apply<<<(N_NODES * HDIM) / 256, 256, 0, stream>>>(
            outb, bns1, bns2, bng + l * HDIM, bnb + l * HDIM, h, hf,
            agg, batch, pooled, cnt, (l == NLAYER - 1) ? 1 : 0);
    }

    k_head<<<NGRAPH, 128, 0, stream>>>(pooled, cnt, hw1, hb1, hw2, hb2, y);
}